// Round 3
// baseline (6291.962 us; speedup 1.0000x reference)
//
#include <hip/hip_runtime.h>
#include <hip/hip_bf16.h>

#define B_ 8
#define C_ 128
#define T_ 16384
#define L_ 20
#define TT 64
#define NTILES (T_ / TT)   // 256

// ---------------------------------------------------------------------------
// Weight prep: transpose to [l][k][m] so GEMM staging loads are coalesced.
// Wd_t[l][k][m], k in [0,256): k<128 -> tap0 (delayed), k>=128 -> tap1 (current)
// (verified against conv semantics: y[t] = w[tap0]*x[t-dil] + w[tap1]*x[t])
// ---------------------------------------------------------------------------
__global__ __launch_bounds__(256) void prep_kernel(
    const float* __restrict__ Wd, const float* __restrict__ Wt,
    const float* __restrict__ Ws, const float* __restrict__ Wk,
    float* __restrict__ Wdt, float* __restrict__ Wtt,
    float* __restrict__ Wst, float* __restrict__ Wkt)
{
    int idx = blockIdx.x * 256 + threadIdx.x;
    const int NWD = L_ * 256 * C_;   // 655360
    const int NW1 = L_ * C_ * C_;    // 327680
    if (idx < NWD) {
        int m = idx & 127;
        int k = (idx >> 7) & 255;
        int l = idx >> 15;
        int i = k & 127, tap = k >> 7;
        Wdt[idx] = Wd[(((size_t)(l * C_ + m)) * C_ + i) * 2 + tap];
        return;
    }
    idx -= NWD;
    if (idx < NW1) {
        int m = idx & 127; int k = (idx >> 7) & 127; int l = idx >> 14;
        Wtt[idx] = Wt[((size_t)(l * C_ + m)) * C_ + k];
        return;
    }
    idx -= NW1;
    if (idx < NW1) {
        int m = idx & 127; int k = (idx >> 7) & 127; int l = idx >> 14;
        Wst[idx] = Ws[((size_t)(l * C_ + m)) * C_ + k];
        return;
    }
    idx -= NW1;
    if (idx < NW1) {
        int m = idx & 127; int k = (idx >> 7) & 127; int l = idx >> 14;
        Wkt[idx] = Wk[((size_t)(l * C_ + m)) * C_ + k];
    }
}

// ---------------------------------------------------------------------------
// Input 1x1 conv (CIN=1): h[b][c][t] = W_in[c] * x[b][t] + b_in[c]
// ---------------------------------------------------------------------------
__global__ __launch_bounds__(256) void in_conv_kernel(
    const float* __restrict__ x, const float* __restrict__ Win,
    const float* __restrict__ bin, float* __restrict__ h)
{
    int idx = blockIdx.x * 256 + threadIdx.x;   // over B*C*(T/4)
    int t4 = idx & (T_ / 4 - 1);                // T/4 = 4096
    int bc = idx >> 12;
    int c = bc & 127;
    float w = Win[c], bias = bin[c];
    const float4 xv = *(const float4*)(x + ((size_t)(bc >> 7)) * T_ + (size_t)t4 * 4);
    float4 o;
    o.x = w * xv.x + bias; o.y = w * xv.y + bias;
    o.z = w * xv.z + bias; o.w = w * xv.w + bias;
    *(float4*)(h + (size_t)bc * T_ + (size_t)t4 * 4) = o;
}

// ---------------------------------------------------------------------------
// Chunked register-blocked GEMM with software-pipelined weight staging:
// chunk k+1's global loads issue BEFORE the barrier, land after the FMA loop
// (~1024cy of cover for ~200-400cy L2 latency -> no per-chunk vmcnt stall).
// acc[r*4+c] += sum_k A[k][m=rg*4+r] * B[k][n=cg*4+c]
// ---------------------------------------------------------------------------
__device__ __forceinline__ void gemm_chunks(
    const float* __restrict__ Ag, const float* __restrict__ Blds,
    float* __restrict__ wch, float (&acc)[16],
    int K, int tid, int rg, int cg)
{
    float4 p0 = *(const float4*)(Ag + tid * 4);
    float4 p1 = *(const float4*)(Ag + (tid + 512) * 4);
    for (int kc = 0; kc < K; kc += 32) {
        int kn = (kc + 32 < K) ? kc + 32 : kc;   // branchless clamp (last-iter loads unused)
        float4 n0 = *(const float4*)(Ag + kn * C_ + tid * 4);
        float4 n1 = *(const float4*)(Ag + kn * C_ + (tid + 512) * 4);
        __syncthreads();
        *(float4*)(&wch[tid * 4])         = p0;
        *(float4*)(&wch[(tid + 512) * 4]) = p1;
        __syncthreads();
        #pragma unroll 8
        for (int k = 0; k < 32; ++k) {
            float4 a = *(const float4*)(&wch[k * C_ + rg * 4]);
            float4 b = *(const float4*)(&Blds[(kc + k) * TT + cg * 4]);
            acc[0]  += a.x * b.x; acc[1]  += a.x * b.y; acc[2]  += a.x * b.z; acc[3]  += a.x * b.w;
            acc[4]  += a.y * b.x; acc[5]  += a.y * b.y; acc[6]  += a.y * b.z; acc[7]  += a.y * b.w;
            acc[8]  += a.z * b.x; acc[9]  += a.z * b.y; acc[10] += a.z * b.z; acc[11] += a.z * b.w;
            acc[12] += a.w * b.x; acc[13] += a.w * b.y; acc[14] += a.w * b.z; acc[15] += a.w * b.w;
        }
        p0 = n0; p1 = n1;
    }
}

// ---------------------------------------------------------------------------
// Dual GEMM, shared B reads, pipelined staging: acc0 += Wt^T B, acc1 += Ws^T B.
// K fixed at 128, 16-k chunks (two 8KB halves of wch).
// ---------------------------------------------------------------------------
__device__ __forceinline__ void gemm_dual(
    const float* __restrict__ Ag0, const float* __restrict__ Ag1,
    const float* __restrict__ Blds,
    float* __restrict__ wch, float (&acc0)[16], float (&acc1)[16],
    int tid, int rg, int cg)
{
    float4 p0 = *(const float4*)(Ag0 + tid * 4);
    float4 p1 = *(const float4*)(Ag1 + tid * 4);
    for (int kc = 0; kc < 128; kc += 16) {
        int kn = (kc + 16 < 128) ? kc + 16 : kc;
        float4 n0 = *(const float4*)(Ag0 + kn * C_ + tid * 4);
        float4 n1 = *(const float4*)(Ag1 + kn * C_ + tid * 4);
        __syncthreads();
        *(float4*)(&wch[tid * 4])        = p0;
        *(float4*)(&wch[2048 + tid * 4]) = p1;
        __syncthreads();
        #pragma unroll 4
        for (int k = 0; k < 16; ++k) {
            float4 a0 = *(const float4*)(&wch[k * C_ + rg * 4]);
            float4 a1 = *(const float4*)(&wch[2048 + k * C_ + rg * 4]);
            float4 b  = *(const float4*)(&Blds[(kc + k) * TT + cg * 4]);
            acc0[0]  += a0.x * b.x; acc0[1]  += a0.x * b.y; acc0[2]  += a0.x * b.z; acc0[3]  += a0.x * b.w;
            acc0[4]  += a0.y * b.x; acc0[5]  += a0.y * b.y; acc0[6]  += a0.y * b.z; acc0[7]  += a0.y * b.w;
            acc0[8]  += a0.z * b.x; acc0[9]  += a0.z * b.y; acc0[10] += a0.z * b.z; acc0[11] += a0.z * b.w;
            acc0[12] += a0.w * b.x; acc0[13] += a0.w * b.y; acc0[14] += a0.w * b.z; acc0[15] += a0.w * b.w;
            acc1[0]  += a1.x * b.x; acc1[1]  += a1.x * b.y; acc1[2]  += a1.x * b.z; acc1[3]  += a1.x * b.w;
            acc1[4]  += a1.y * b.x; acc1[5]  += a1.y * b.y; acc1[6]  += a1.y * b.z; acc1[7]  += a1.y * b.w;
            acc1[8]  += a1.z * b.x; acc1[9]  += a1.z * b.y; acc1[10] += a1.z * b.z; acc1[11] += a1.z * b.w;
            acc1[12] += a1.w * b.x; acc1[13] += a1.w * b.y; acc1[14] += a1.w * b.z; acc1[15] += a1.w * b.w;
        }
        p0 = n0; p1 = n1;
    }
}

// ---------------------------------------------------------------------------
// One WaveNet layer, fully fused. LDS plan (80KB total -> 2 blocks/CU):
//   bops[256*TT] (64KB): Phase A/B = [h_del ; h_cur]. After Phase B the
//   buffer is dead and re-used: rows 0..127 <- xd, rows 128..255 <- xh.
//   wch[4096] (16KB): weight-chunk staging.
// ---------------------------------------------------------------------------
__global__ __launch_bounds__(512, 4) void layer_kernel(
    const float* __restrict__ h_in, float* __restrict__ h_out,
    float* __restrict__ skip,
    const float* __restrict__ Wd, const float* __restrict__ Wt,
    const float* __restrict__ Ws, const float* __restrict__ Wk,
    const float* __restrict__ bd, const float* __restrict__ bt,
    const float* __restrict__ bs, const float* __restrict__ bk,
    int dil, int addskip)
{
    __shared__ float bops[256 * TT];  // 64KB
    __shared__ float wch[32 * C_];    // 16KB

    const int tid = threadIdx.x;
    const int b  = blockIdx.x / NTILES;
    const int t0 = (blockIdx.x % NTILES) * TT;
    const float* hb = h_in + (size_t)b * C_ * T_;

    // --- Phase A: stage h tiles ---
    #pragma unroll
    for (int j = 0; j < 4; ++j) {               // current tap -> rows 128..255
        int s4 = tid + j * 512;
        int c  = s4 >> 4;
        int tt = (s4 & 15) << 2;
        *(float4*)(&bops[(128 + c) * TT + tt]) =
            *(const float4*)(hb + (size_t)c * T_ + t0 + tt);
    }
    if ((dil & 3) == 0) {                       // delayed tap, 16B-aligned path
        #pragma unroll
        for (int j = 0; j < 4; ++j) {
            int s4 = tid + j * 512;
            int c  = s4 >> 4;
            int tt = (s4 & 15) << 2;
            int tg = t0 + tt - dil;
            float4 v = make_float4(0.f, 0.f, 0.f, 0.f);
            if (tg >= 0) v = *(const float4*)(hb + (size_t)c * T_ + tg);
            *(float4*)(&bops[c * TT + tt]) = v;
        }
    } else {                                    // dil = 1,2: scalar path
        #pragma unroll
        for (int j = 0; j < 16; ++j) {
            int s  = tid + j * 512;
            int c  = s >> 6;
            int tt = s & 63;
            int tg = t0 + tt - dil;
            bops[c * TT + tt] = (tg >= 0) ? hb[(size_t)c * T_ + tg] : 0.f;
        }
    }

    const int rg = tid >> 4;   // row group: rows rg*4 .. rg*4+3
    const int cg = tid & 15;   // col group: cols cg*4 .. cg*4+3

    // --- Phase B: xd = Wd @ [h_del; h_cur] + bd ---
    float acc[16];
    #pragma unroll
    for (int i = 0; i < 16; ++i) acc[i] = 0.f;
    gemm_chunks(Wd, bops, wch, acc, 256, tid, rg, cg);

    __syncthreads();   // all Phase-B reads of bops complete before overwrite
    float* xd = bops;              // rows 0..127
    float* xh = bops + 128 * TT;   // rows 128..255
    {
        float4 bv = *(const float4*)(bd + rg * 4);
        float bb[4] = {bv.x, bv.y, bv.z, bv.w};
        #pragma unroll
        for (int r = 0; r < 4; ++r) {
            float4 o;
            o.x = acc[r*4+0] + bb[r]; o.y = acc[r*4+1] + bb[r];
            o.z = acc[r*4+2] + bb[r]; o.w = acc[r*4+3] + bb[r];
            *(float4*)(&xd[(rg * 4 + r) * TT + cg * 4]) = o;
        }
    }

    // --- Phase C: gates (dual GEMM, shared B reads; leading sync in
    //     gemm_dual orders the xd writes above before any wch overwrite) ---
    float acct[16], accs[16];
    #pragma unroll
    for (int i = 0; i < 16; ++i) { acct[i] = 0.f; accs[i] = 0.f; }
    gemm_dual(Wt, Ws, xd, wch, acct, accs, tid, rg, cg);

    float xhv[16];
    {
        float4 btv = *(const float4*)(bt + rg * 4);
        float4 bsv = *(const float4*)(bs + rg * 4);
        float btA[4] = {btv.x, btv.y, btv.z, btv.w};
        float bsA[4] = {bsv.x, bsv.y, bsv.z, bsv.w};
        #pragma unroll
        for (int r = 0; r < 4; ++r) {
            #pragma unroll
            for (int c2 = 0; c2 < 4; ++c2) {
                float at = acct[r*4+c2] + btA[r];
                float as = accs[r*4+c2] + bsA[r];
                float f = 2.f / (1.f + __expf(-2.f * at)) - 1.f;  // tanh
                float g = 1.f / (1.f + __expf(-as));              // sigmoid
                xhv[r*4+c2] = f * g;
            }
            // writes rows 128..255 only — no conflict with Phase C reads (rows 0..127)
            float4 o;
            o.x = xhv[r*4+0]; o.y = xhv[r*4+1]; o.z = xhv[r*4+2]; o.w = xhv[r*4+3];
            *(float4*)(&xh[(rg * 4 + r) * TT + cg * 4]) = o;
        }
    }

    // --- h_out = xh + xd (register xhv + register acc + bias) ---
    {
        float4 bv = *(const float4*)(bd + rg * 4);
        float bb[4] = {bv.x, bv.y, bv.z, bv.w};
        float* hob = h_out + (size_t)b * C_ * T_;
        #pragma unroll
        for (int r = 0; r < 4; ++r) {
            float4 o;
            o.x = xhv[r*4+0] + acc[r*4+0] + bb[r];
            o.y = xhv[r*4+1] + acc[r*4+1] + bb[r];
            o.z = xhv[r*4+2] + acc[r*4+2] + bb[r];
            o.w = xhv[r*4+3] + acc[r*4+3] + bb[r];
            *(float4*)(hob + (size_t)(rg * 4 + r) * T_ + t0 + cg * 4) = o;
        }
    }

    // --- Phase D: skip += Wk @ xh + bk (leading sync orders xh writes) ---
    float acck[16];
    #pragma unroll
    for (int i = 0; i < 16; ++i) acck[i] = 0.f;
    gemm_chunks(Wk, xh, wch, acck, 128, tid, rg, cg);
    {
        float4 bkv = *(const float4*)(bk + rg * 4);
        float bkA[4] = {bkv.x, bkv.y, bkv.z, bkv.w};
        float* skb = skip + (size_t)b * C_ * T_;
        #pragma unroll
        for (int r = 0; r < 4; ++r) {
            float4 o;
            o.x = acck[r*4+0] + bkA[r]; o.y = acck[r*4+1] + bkA[r];
            o.z = acck[r*4+2] + bkA[r]; o.w = acck[r*4+3] + bkA[r];
            if (addskip) {
                float4 s = *(const float4*)(skb + (size_t)(rg * 4 + r) * T_ + t0 + cg * 4);
                o.x += s.x; o.y += s.y; o.z += s.z; o.w += s.w;
            }
            *(float4*)(skb + (size_t)(rg * 4 + r) * T_ + t0 + cg * 4) = o;
        }
    }
}

// ---------------------------------------------------------------------------
extern "C" void kernel_launch(void* const* d_in, const int* in_sizes, int n_in,
                              void* d_out, int out_size, void* d_ws, size_t ws_size,
                              hipStream_t stream)
{
    const float* x   = (const float*)d_in[0];
    const float* Win = (const float*)d_in[1];
    const float* bin = (const float*)d_in[2];
    const float* Wd  = (const float*)d_in[3];
    const float* bd  = (const float*)d_in[4];
    const float* Wt  = (const float*)d_in[5];
    const float* bt  = (const float*)d_in[6];
    const float* Ws  = (const float*)d_in[7];
    const float* bs  = (const float*)d_in[8];
    const float* Wk  = (const float*)d_in[9];
    const float* bk  = (const float*)d_in[10];
    float* out = (float*)d_out;

    float* ws  = (float*)d_ws;
    const size_t HN = (size_t)B_ * C_ * T_;           // 16,777,216 floats (64MB)
    float* hA  = ws;
    float* hB  = ws + HN;
    float* Wdt = ws + 2 * HN;
    float* Wtt = Wdt + (size_t)L_ * 256 * C_;
    float* Wst = Wtt + (size_t)L_ * C_ * C_;
    float* Wkt = Wst + (size_t)L_ * C_ * C_;
    // ws usage: 2*64MB h ping-pong + 6.6MB weights = ~135MB

    const int prep_total = L_ * 256 * C_ + 3 * L_ * C_ * C_;  // 1,638,400
    prep_kernel<<<(prep_total + 255) / 256, 256, 0, stream>>>(Wd, Wt, Ws, Wk,
                                                              Wdt, Wtt, Wst, Wkt);
    in_conv_kernel<<<(B_ * C_ * (T_ / 4)) / 256, 256, 0, stream>>>(x, Win, bin, hA);

    float* hin = hA;
    float* hout = hB;
    for (int l = 0; l < L_; ++l) {
        int dil = 1 << (l % 10);
        layer_kernel<<<B_ * NTILES, 512, 0, stream>>>(
            hin, hout, out,
            Wdt + (size_t)l * 256 * C_, Wtt + (size_t)l * C_ * C_,
            Wst + (size_t)l * C_ * C_, Wkt + (size_t)l * C_ * C_,
            bd + l * C_, bt + l * C_, bs + l * C_, bk + l * C_,
            dil, l > 0 ? 1 : 0);
        float* tmp = hin; hin = hout; hout = tmp;
    }
}

// Round 4
// 2777.907 us; speedup vs baseline: 2.2650x; 2.2650x over previous
//
#include <hip/hip_runtime.h>

#define B_ 8
#define C_ 128
#define T_ 16384
#define L_ 20
#define TN 128            // time-cols per block
#define NTL (T_ / TN)     // 128 tiles per batch
#define XROW 136          // Xb row stride in ushorts (128 + 8 pad; 272B, 16B-mult)
#define WROW 40           // weight-chunk row stride in ushorts (32 + 8 pad; 80B)

typedef short bf16x8 __attribute__((ext_vector_type(8)));
typedef float f32x16 __attribute__((ext_vector_type(16)));

// ---------------------------------------------------------------------------
// bf16 split helpers: x ~= hi + lo, both RNE bf16 -> ~2^-17 relative capture
// ---------------------------------------------------------------------------
__device__ __forceinline__ ushort bf16_rn(float v) {
    union { float f; unsigned u; } a; a.f = v;
    unsigned r = (a.u + 0x7FFFu + ((a.u >> 16) & 1u)) >> 16;
    return (ushort)r;
}
__device__ __forceinline__ float bf16_to_f(ushort h) {
    union { unsigned u; float f; } b; b.u = ((unsigned)h) << 16;
    return b.f;
}
__device__ __forceinline__ void split2(float v, ushort& hh, ushort& ll) {
    ushort h = bf16_rn(v);
    hh = h;
    ll = bf16_rn(v - bf16_to_f(h));
}

// ---------------------------------------------------------------------------
// Weight prep: transpose Wd to [l][m][k(256)] (k<128 = delayed tap0, k>=128 =
// current tap1); Wt/Ws/Wk already [l][m][k]. Split every element to hi/lo bf16.
// ---------------------------------------------------------------------------
__global__ __launch_bounds__(256) void prep_kernel(
    const float* __restrict__ Wd, const float* __restrict__ Wt,
    const float* __restrict__ Ws, const float* __restrict__ Wk,
    ushort* __restrict__ WdH, ushort* __restrict__ WdL,
    ushort* __restrict__ WtH, ushort* __restrict__ WtL,
    ushort* __restrict__ WsH, ushort* __restrict__ WsL,
    ushort* __restrict__ WkH, ushort* __restrict__ WkL)
{
    int idx = blockIdx.x * 256 + threadIdx.x;
    const int ND = L_ * C_ * 256;   // 655360
    const int N1 = L_ * C_ * C_;    // 327680
    float v; ushort* oH; ushort* oL; int o;
    if (idx < ND) {
        int k = idx & 255, m = (idx >> 8) & 127, l = idx >> 15;
        v = Wd[(((size_t)(l * C_ + m)) * C_ + (k & 127)) * 2 + (k >> 7)];
        oH = WdH; oL = WdL; o = idx;
    } else {
        int i2 = idx - ND;
        if (i2 < N1)            { v = Wt[i2]; oH = WtH; oL = WtL; o = i2; }
        else if (i2 < 2 * N1)   { o = i2 - N1;     v = Ws[o]; oH = WsH; oL = WsL; }
        else if (i2 < 3 * N1)   { o = i2 - 2 * N1; v = Wk[o]; oH = WkH; oL = WkL; }
        else return;
    }
    ushort h, l; split2(v, h, l);
    oH[o] = h; oL[o] = l;
}

// ---------------------------------------------------------------------------
// Input 1x1 conv (CIN=1): h[b][c][t] = W_in[c] * x[b][t] + b_in[c]  (fp32)
// ---------------------------------------------------------------------------
__global__ __launch_bounds__(256) void in_conv_kernel(
    const float* __restrict__ x, const float* __restrict__ Win,
    const float* __restrict__ bin, float* __restrict__ h)
{
    int idx = blockIdx.x * 256 + threadIdx.x;
    int t4 = idx & (T_ / 4 - 1);
    int bc = idx >> 12;
    int c = bc & 127;
    float w = Win[c], bias = bin[c];
    const float4 xv = *(const float4*)(x + ((size_t)(bc >> 7)) * T_ + (size_t)t4 * 4);
    float4 o;
    o.x = w * xv.x + bias; o.y = w * xv.y + bias;
    o.z = w * xv.z + bias; o.w = w * xv.w + bias;
    *(float4*)(h + (size_t)bc * T_ + (size_t)t4 * 4) = o;
}

// ---------------------------------------------------------------------------
// Stage a [128 ch][TN t] fp32 tile from global into Xb as hi/lo bf16,
// layout Xb[n=t][k=c] (row stride XROW). tbase may be t0-dil (zero-pad t<0).
// ---------------------------------------------------------------------------
__device__ __forceinline__ void stageX(
    const float* __restrict__ hb, int tbase,
    ushort* __restrict__ XH, ushort* __restrict__ XL)
{
    __syncthreads();                    // prior readers of Xb done
    const int tid = threadIdx.x;
    const int tl = tid & 127, cg = tid >> 7;
    const int tg = tbase + tl;
    const bool ok = (tg >= 0);
    #pragma unroll
    for (int j = 0; j < 8; ++j) {
        int c0 = cg * 32 + j * 4;
        float v0 = ok ? hb[(c0 + 0) * T_ + tg] : 0.f;
        float v1 = ok ? hb[(c0 + 1) * T_ + tg] : 0.f;
        float v2 = ok ? hb[(c0 + 2) * T_ + tg] : 0.f;
        float v3 = ok ? hb[(c0 + 3) * T_ + tg] : 0.f;
        ushort4 h4, l4;
        split2(v0, h4.x, l4.x); split2(v1, h4.y, l4.y);
        split2(v2, h4.z, l4.z); split2(v3, h4.w, l4.w);
        *(ushort4*)&XH[tl * XROW + c0] = h4;
        *(ushort4*)&XL[tl * XROW + c0] = l4;
    }
    __syncthreads();                    // Xb visible to all
}

// ---------------------------------------------------------------------------
// Split-bf16 GEMM over one staged Xb (K=128 local), weights streamed in k32
// chunks with register prefetch. acc[mi] (mi=2 m-frags of 32 rows) += W^T X.
// 3 MFMA passes per frag-pair: hi*hi + hi*lo + lo*hi.
// ---------------------------------------------------------------------------
__device__ __forceinline__ void gemm_one(
    const ushort* __restrict__ gH, const ushort* __restrict__ gL,
    int rowlen, int kw0,
    ushort* __restrict__ sH, ushort* __restrict__ sL,
    const ushort* __restrict__ XH, const ushort* __restrict__ XL,
    int m_wave, int n_wave, int ln31, int kg,
    f32x16 (&acc)[2])
{
    const int tid = threadIdx.x;
    const int sm = tid >> 2, sk = (tid & 3) * 8;
    const int gbase = sm * rowlen + kw0 + sk;
    uint4 pH = *(const uint4*)(gH + gbase);
    uint4 pL = *(const uint4*)(gL + gbase);
    #pragma unroll
    for (int c = 0; c < 4; ++c) {
        __syncthreads();
        *(uint4*)&sH[sm * WROW + sk] = pH;
        *(uint4*)&sL[sm * WROW + sk] = pL;
        int kn = (c < 3) ? (c + 1) * 32 : 3 * 32;
        pH = *(const uint4*)(gH + gbase + kn);
        pL = *(const uint4*)(gL + gbase + kn);
        __syncthreads();
        #pragma unroll
        for (int ks = 0; ks < 32; ks += 16) {
            bf16x8 bh = *(const bf16x8*)&XH[(n_wave + ln31) * XROW + c * 32 + ks + kg];
            bf16x8 bl = *(const bf16x8*)&XL[(n_wave + ln31) * XROW + c * 32 + ks + kg];
            #pragma unroll
            for (int mi = 0; mi < 2; ++mi) {
                bf16x8 ah = *(const bf16x8*)&sH[(m_wave + mi * 32 + ln31) * WROW + ks + kg];
                bf16x8 al = *(const bf16x8*)&sL[(m_wave + mi * 32 + ln31) * WROW + ks + kg];
                acc[mi] = __builtin_amdgcn_mfma_f32_32x32x16_bf16(ah, bh, acc[mi], 0, 0, 0);
                acc[mi] = __builtin_amdgcn_mfma_f32_32x32x16_bf16(ah, bl, acc[mi], 0, 0, 0);
                acc[mi] = __builtin_amdgcn_mfma_f32_32x32x16_bf16(al, bh, acc[mi], 0, 0, 0);
            }
        }
    }
}

// Dual GEMM (Wt and Ws) sharing the B-operand reads.
__device__ __forceinline__ void gemm_two(
    const ushort* __restrict__ gH0, const ushort* __restrict__ gL0,
    const ushort* __restrict__ gH1, const ushort* __restrict__ gL1,
    ushort* __restrict__ sH0, ushort* __restrict__ sL0,
    ushort* __restrict__ sH1, ushort* __restrict__ sL1,
    const ushort* __restrict__ XH, const ushort* __restrict__ XL,
    int m_wave, int n_wave, int ln31, int kg,
    f32x16 (&a0)[2], f32x16 (&a1)[2])
{
    const int tid = threadIdx.x;
    const int sm = tid >> 2, sk = (tid & 3) * 8;
    const int gbase = sm * 128 + sk;
    uint4 pH0 = *(const uint4*)(gH0 + gbase);
    uint4 pL0 = *(const uint4*)(gL0 + gbase);
    uint4 pH1 = *(const uint4*)(gH1 + gbase);
    uint4 pL1 = *(const uint4*)(gL1 + gbase);
    #pragma unroll
    for (int c = 0; c < 4; ++c) {
        __syncthreads();
        *(uint4*)&sH0[sm * WROW + sk] = pH0;
        *(uint4*)&sL0[sm * WROW + sk] = pL0;
        *(uint4*)&sH1[sm * WROW + sk] = pH1;
        *(uint4*)&sL1[sm * WROW + sk] = pL1;
        int kn = (c < 3) ? (c + 1) * 32 : 3 * 32;
        pH0 = *(const uint4*)(gH0 + gbase + kn);
        pL0 = *(const uint4*)(gL0 + gbase + kn);
        pH1 = *(const uint4*)(gH1 + gbase + kn);
        pL1 = *(const uint4*)(gL1 + gbase + kn);
        __syncthreads();
        #pragma unroll
        for (int ks = 0; ks < 32; ks += 16) {
            bf16x8 bh = *(const bf16x8*)&XH[(n_wave + ln31) * XROW + c * 32 + ks + kg];
            bf16x8 bl = *(const bf16x8*)&XL[(n_wave + ln31) * XROW + c * 32 + ks + kg];
            #pragma unroll
            for (int mi = 0; mi < 2; ++mi) {
                int ai = (m_wave + mi * 32 + ln31) * WROW + ks + kg;
                bf16x8 ah0 = *(const bf16x8*)&sH0[ai];
                bf16x8 al0 = *(const bf16x8*)&sL0[ai];
                bf16x8 ah1 = *(const bf16x8*)&sH1[ai];
                bf16x8 al1 = *(const bf16x8*)&sL1[ai];
                a0[mi] = __builtin_amdgcn_mfma_f32_32x32x16_bf16(ah0, bh, a0[mi], 0, 0, 0);
                a0[mi] = __builtin_amdgcn_mfma_f32_32x32x16_bf16(ah0, bl, a0[mi], 0, 0, 0);
                a0[mi] = __builtin_amdgcn_mfma_f32_32x32x16_bf16(al0, bh, a0[mi], 0, 0, 0);
                a1[mi] = __builtin_amdgcn_mfma_f32_32x32x16_bf16(ah1, bh, a1[mi], 0, 0, 0);
                a1[mi] = __builtin_amdgcn_mfma_f32_32x32x16_bf16(ah1, bl, a1[mi], 0, 0, 0);
                a1[mi] = __builtin_amdgcn_mfma_f32_32x32x16_bf16(al1, bh, a1[mi], 0, 0, 0);
            }
        }
    }
}

// ---------------------------------------------------------------------------
// One WaveNet layer, fused, split-bf16 MFMA.
// Block: M=128 (all channels) x N=TN=128 times; 8 waves as 2(m) x 4(n),
// wave tile 64x32, 2 m-frags of 32x32 per wave, acc = 2 x f32x16.
// D-frag mapping (verified m74/m101): col n = lane&31,
// row m = (r&3) + 8*(r>>2) + 4*(lane>>5).
// ---------------------------------------------------------------------------
__global__ __launch_bounds__(512, 2) void layer_kernel(
    const float* __restrict__ h_in, float* __restrict__ h_out,
    float* __restrict__ skip,
    const ushort* __restrict__ WdH, const ushort* __restrict__ WdL,
    const ushort* __restrict__ WtH, const ushort* __restrict__ WtL,
    const ushort* __restrict__ WsH, const ushort* __restrict__ WsL,
    const ushort* __restrict__ WkH, const ushort* __restrict__ WkL,
    const float* __restrict__ bd, const float* __restrict__ bt,
    const float* __restrict__ bs, const float* __restrict__ bk,
    int dil, int addskip)
{
    __shared__ ushort XbH[TN * XROW], XbL[TN * XROW];   // 2 x 34 KB
    __shared__ ushort WaH[C_ * WROW], WaL[C_ * WROW];   // 2 x 10 KB
    __shared__ ushort WbH[C_ * WROW], WbL[C_ * WROW];   // 2 x 10 KB
    __shared__ float bias_lds[512];                     // bd|bt|bs|bk

    const int tid = threadIdx.x;
    const int b  = blockIdx.x / NTL;
    const int t0 = (blockIdx.x % NTL) * TN;
    const int lane = tid & 63;
    const int wave = tid >> 6;
    const int m_wave = (wave & 1) * 64;
    const int n_wave = (wave >> 1) * 32;
    const int ln31 = lane & 31, kg = (lane >> 5) * 8, hi5 = lane >> 5;
    const float* hb = h_in + (size_t)b * C_ * T_;

    {   // biases -> LDS (barriers below order this before first use)
        int sec = tid >> 7;
        const float* bp = sec == 0 ? bd : (sec == 1 ? bt : (sec == 2 ? bs : bk));
        bias_lds[tid] = bp[tid & 127];
    }

    // ---- Phase B: xd = Wd @ [h_del ; h_cur] + bd  (K=256 in two halves) ----
    f32x16 xdacc[2];
    #pragma unroll
    for (int mi = 0; mi < 2; ++mi)
        #pragma unroll
        for (int r = 0; r < 16; ++r) xdacc[mi][r] = 0.f;

    stageX(hb, t0 - dil, XbH, XbL);
    gemm_one(WdH, WdL, 256, 0,   WaH, WaL, XbH, XbL, m_wave, n_wave, ln31, kg, xdacc);
    stageX(hb, t0,       XbH, XbL);
    gemm_one(WdH, WdL, 256, 128, WaH, WaL, XbH, XbL, m_wave, n_wave, ln31, kg, xdacc);

    // epilogue: add bias, keep xd in regs, write xd hi/lo to Xb[n][k=c]
    __syncthreads();                       // all B-GEMM reads of Xb done
    const int nn = n_wave + ln31;
    #pragma unroll
    for (int mi = 0; mi < 2; ++mi) {
        #pragma unroll
        for (int g = 0; g < 4; ++g) {
            int mloc = m_wave + mi * 32 + g * 8 + 4 * hi5;
            const float* bb = &bias_lds[mloc];          // bd section
            ushort4 h4, l4;
            float v0 = xdacc[mi][g * 4 + 0] + bb[0]; xdacc[mi][g * 4 + 0] = v0;
            float v1 = xdacc[mi][g * 4 + 1] + bb[1]; xdacc[mi][g * 4 + 1] = v1;
            float v2 = xdacc[mi][g * 4 + 2] + bb[2]; xdacc[mi][g * 4 + 2] = v2;
            float v3 = xdacc[mi][g * 4 + 3] + bb[3]; xdacc[mi][g * 4 + 3] = v3;
            split2(v0, h4.x, l4.x); split2(v1, h4.y, l4.y);
            split2(v2, h4.z, l4.z); split2(v3, h4.w, l4.w);
            *(ushort4*)&XbH[nn * XROW + mloc] = h4;
            *(ushort4*)&XbL[nn * XROW + mloc] = l4;
        }
    }

    // ---- Phase C: gates (dual GEMM over xd) ----
    f32x16 at[2], as_[2];
    #pragma unroll
    for (int mi = 0; mi < 2; ++mi)
        #pragma unroll
        for (int r = 0; r < 16; ++r) { at[mi][r] = 0.f; as_[mi][r] = 0.f; }
    gemm_two(WtH, WtL, WsH, WsL, WaH, WaL, WbH, WbL,
             XbH, XbL, m_wave, n_wave, ln31, kg, at, as_);

    __syncthreads();                       // all C-GEMM reads of Xb done
    float* hob = h_out + (size_t)b * C_ * T_;
    f32x16 xhv[2];
    #pragma unroll
    for (int mi = 0; mi < 2; ++mi) {
        #pragma unroll
        for (int g = 0; g < 4; ++g) {
            int mloc = m_wave + mi * 32 + g * 8 + 4 * hi5;
            const float* btp = &bias_lds[128 + mloc];
            const float* bsp = &bias_lds[256 + mloc];
            ushort4 h4, l4;
            #pragma unroll
            for (int j = 0; j < 4; ++j) {
                float a = at[mi][g * 4 + j] + btp[j];
                float s = as_[mi][g * 4 + j] + bsp[j];
                float f  = 2.f / (1.f + __expf(-2.f * a)) - 1.f;   // tanh
                float gg = 1.f / (1.f + __expf(-s));               // sigmoid
                float xh = f * gg;
                xhv[mi][g * 4 + j] = xh;
                ushort hh, ll; split2(xh, hh, ll);
                ((ushort*)&h4)[j] = hh; ((ushort*)&l4)[j] = ll;
                hob[(size_t)(mloc + j) * T_ + t0 + nn] = xh + xdacc[mi][g * 4 + j];
            }
            *(ushort4*)&XbH[nn * XROW + mloc] = h4;    // xh overwrites xd in Xb
            *(ushort4*)&XbL[nn * XROW + mloc] = l4;
        }
    }

    // ---- Phase D: skip += Wk @ xh + bk ----
    f32x16 ak[2];
    #pragma unroll
    for (int mi = 0; mi < 2; ++mi)
        #pragma unroll
        for (int r = 0; r < 16; ++r) ak[mi][r] = 0.f;
    gemm_one(WkH, WkL, 128, 0, WaH, WaL, XbH, XbL, m_wave, n_wave, ln31, kg, ak);

    float* skb = skip + (size_t)b * C_ * T_;
    #pragma unroll
    for (int mi = 0; mi < 2; ++mi) {
        #pragma unroll
        for (int g = 0; g < 4; ++g) {
            int mloc = m_wave + mi * 32 + g * 8 + 4 * hi5;
            const float* bkp = &bias_lds[384 + mloc];
            #pragma unroll
            for (int j = 0; j < 4; ++j) {
                float v = ak[mi][g * 4 + j] + bkp[j];
                size_t adr = (size_t)(mloc + j) * T_ + t0 + nn;
                if (addskip) v += skb[adr];
                skb[adr] = v;
            }
        }
    }
}

// ---------------------------------------------------------------------------
extern "C" void kernel_launch(void* const* d_in, const int* in_sizes, int n_in,
                              void* d_out, int out_size, void* d_ws, size_t ws_size,
                              hipStream_t stream)
{
    const float* x   = (const float*)d_in[0];
    const float* Win = (const float*)d_in[1];
    const float* bin = (const float*)d_in[2];
    const float* Wd  = (const float*)d_in[3];
    const float* bd  = (const float*)d_in[4];
    const float* Wt  = (const float*)d_in[5];
    const float* bt  = (const float*)d_in[6];
    const float* Ws  = (const float*)d_in[7];
    const float* bs  = (const float*)d_in[8];
    const float* Wk  = (const float*)d_in[9];
    const float* bk  = (const float*)d_in[10];
    float* out = (float*)d_out;

    float* ws = (float*)d_ws;
    const size_t HN = (size_t)B_ * C_ * T_;      // 16.8M floats (64MB)
    float* hA = ws;
    float* hB = ws + HN;
    ushort* wb = (ushort*)(ws + 2 * HN);
    const size_t ND = (size_t)L_ * C_ * 256;     // 655360
    const size_t N1 = (size_t)L_ * C_ * C_;      // 327680
    ushort* WdH = wb;            ushort* WdL = WdH + ND;
    ushort* WtH = WdL + ND;      ushort* WtL = WtH + N1;
    ushort* WsH = WtL + N1;      ushort* WsL = WsH + N1;
    ushort* WkH = WsL + N1;      ushort* WkL = WkH + N1;

    const int prep_total = (int)(ND + 3 * N1);   // 1,638,400
    prep_kernel<<<(prep_total + 255) / 256, 256, 0, stream>>>(
        Wd, Wt, Ws, Wk, WdH, WdL, WtH, WtL, WsH, WsL, WkH, WkL);
    in_conv_kernel<<<(B_ * C_ * (T_ / 4)) / 256, 256, 0, stream>>>(x, Win, bin, hA);

    float* hin = hA;
    float* hout = hB;
    for (int l = 0; l < L_; ++l) {
        int dil = 1 << (l % 10);
        layer_kernel<<<B_ * NTL, 512, 0, stream>>>(
            hin, hout, out,
            WdH + (size_t)l * C_ * 256, WdL + (size_t)l * C_ * 256,
            WtH + (size_t)l * C_ * C_,  WtL + (size_t)l * C_ * C_,
            WsH + (size_t)l * C_ * C_,  WsL + (size_t)l * C_ * C_,
            WkH + (size_t)l * C_ * C_,  WkL + (size_t)l * C_ * C_,
            bd + l * C_, bt + l * C_, bs + l * C_, bk + l * C_,
            dil, l > 0 ? 1 : 0);
        float* tmp = hin; hin = hout; hout = tmp;
    }
}

// Round 5
// 2359.916 us; speedup vs baseline: 2.6662x; 1.1771x over previous
//
#include <hip/hip_runtime.h>

#define B_ 8
#define C_ 128
#define T_ 16384
#define L_ 20
#define TN 128            // time-cols per block
#define NTL (T_ / TN)     // 128 tiles per batch
#define XROW 128          // Xb row stride (ushorts); XOR-swizzled, no pad
#define WROW 16           // weight chunk row stride (ushorts); pair-swizzled

typedef short bf16x8 __attribute__((ext_vector_type(8)));
typedef float f32x16 __attribute__((ext_vector_type(16)));
typedef unsigned short u16x8 __attribute__((ext_vector_type(8)));

// ---------------------------------------------------------------------------
// bf16 split helpers: x ~= hi + lo, both RNE bf16 -> ~2^-17 relative capture
// ---------------------------------------------------------------------------
__device__ __forceinline__ ushort bf16_rn(float v) {
    union { float f; unsigned u; } a; a.f = v;
    unsigned r = (a.u + 0x7FFFu + ((a.u >> 16) & 1u)) >> 16;
    return (ushort)r;
}
__device__ __forceinline__ float bf16_to_f(ushort h) {
    union { unsigned u; float f; } b; b.u = ((unsigned)h) << 16;
    return b.f;
}
__device__ __forceinline__ void split2(float v, ushort& hh, ushort& ll) {
    ushort h = bf16_rn(v);
    hh = h;
    ll = bf16_rn(v - bf16_to_f(h));
}

// ---------------------------------------------------------------------------
// Weight prep into k16-chunked, pair-swizzled layout:
//   dest(l,m,k) = base_l + (k>>4)*2048 + m*16 + ((k&15) ^ ((m&1)<<3))
// Wd additionally transposed to A[m][k(256)]: k<128 = tap0 (delayed tile),
// k>=128 = tap1 (current tile). Swizzle rides along the linear LDS copy and
// makes the A-fragment ds_read_b128 bank-conflict-free at WROW=16 (no pad).
// ---------------------------------------------------------------------------
__global__ __launch_bounds__(256) void prep_kernel(
    const float* __restrict__ Wd, const float* __restrict__ Wt,
    const float* __restrict__ Ws, const float* __restrict__ Wk,
    ushort* __restrict__ WdH, ushort* __restrict__ WdL,
    ushort* __restrict__ WtH, ushort* __restrict__ WtL,
    ushort* __restrict__ WsH, ushort* __restrict__ WsL,
    ushort* __restrict__ WkH, ushort* __restrict__ WkL)
{
    int idx = blockIdx.x * 256 + threadIdx.x;
    const int ND = L_ * C_ * 256;   // 655360
    const int N1 = L_ * C_ * C_;    // 327680
    float v; ushort* oH; ushort* oL; int o;
    if (idx < ND) {
        int k = idx & 255, m = (idx >> 8) & 127, l = idx >> 15;
        v = Wd[(((size_t)(l * C_ + m)) * C_ + (k & 127)) * 2 + (k >> 7)];
        o = l * (C_ * 256) + (k >> 4) * 2048 + m * WROW + ((k & 15) ^ ((m & 1) << 3));
        oH = WdH; oL = WdL;
    } else {
        int i2 = idx - ND;
        const float* src;
        if (i2 < N1)           { src = Wt; oH = WtH; oL = WtL; }
        else if (i2 < 2 * N1)  { i2 -= N1;     src = Ws; oH = WsH; oL = WsL; }
        else if (i2 < 3 * N1)  { i2 -= 2 * N1; src = Wk; oH = WkH; oL = WkL; }
        else return;
        int k = i2 & 127, m = (i2 >> 7) & 127, l = i2 >> 14;
        v = src[i2];
        o = l * (C_ * C_) + (k >> 4) * 2048 + m * WROW + ((k & 15) ^ ((m & 1) << 3));
    }
    ushort h, l2; split2(v, h, l2);
    oH[o] = h; oL[o] = l2;
}

// ---------------------------------------------------------------------------
// Input 1x1 conv (CIN=1): h[b][c][t] = W_in[c] * x[b][t] + b_in[c]  (fp32)
// ---------------------------------------------------------------------------
__global__ __launch_bounds__(256) void in_conv_kernel(
    const float* __restrict__ x, const float* __restrict__ Win,
    const float* __restrict__ bin, float* __restrict__ h)
{
    int idx = blockIdx.x * 256 + threadIdx.x;
    int t4 = idx & (T_ / 4 - 1);
    int bc = idx >> 12;
    int c = bc & 127;
    float w = Win[c], bias = bin[c];
    const float4 xv = *(const float4*)(x + ((size_t)(bc >> 7)) * T_ + (size_t)t4 * 4);
    float4 o;
    o.x = w * xv.x + bias; o.y = w * xv.y + bias;
    o.z = w * xv.z + bias; o.w = w * xv.w + bias;
    *(float4*)(h + (size_t)bc * T_ + (size_t)t4 * 4) = o;
}

// ---------------------------------------------------------------------------
// Stage [128 ch][TN t] fp32 tile into Xb hi/lo bf16, layout Xb[t][c] with
// XOR swizzle col ^= (row&7)<<3 (16B-slot spread -> conflict-free b128 reads
// and u16x8 writes). tbase may be t0-dil (zero-pad t<0).
// ---------------------------------------------------------------------------
__device__ __forceinline__ void stageX(
    const float* __restrict__ hb, int tbase,
    ushort* __restrict__ XH, ushort* __restrict__ XL)
{
    __syncthreads();                    // prior readers of Xb done
    const int tid = threadIdx.x;
    const int tl = tid & 127, cg = tid >> 7;
    const int tg = tbase + tl;
    const bool ok = (tg >= 0);
    const int sw = (tl & 7) << 3;
    #pragma unroll
    for (int j = 0; j < 4; ++j) {
        int c0 = cg * 32 + j * 8;
        u16x8 h8, l8;
        #pragma unroll
        for (int i = 0; i < 8; ++i) {
            float v = ok ? hb[(size_t)(c0 + i) * T_ + tg] : 0.f;
            ushort hh, ll; split2(v, hh, ll);
            h8[i] = hh; l8[i] = ll;
        }
        *(u16x8*)&XH[tl * XROW + (c0 ^ sw)] = h8;
        *(u16x8*)&XL[tl * XROW + (c0 ^ sw)] = l8;
    }
    __syncthreads();                    // Xb visible to all
}

// ---------------------------------------------------------------------------
// Split-bf16 GEMM over staged Xb, 8 chunks of k=16, register-prefetched
// weight stream. acc[mi] += W^T X for the wave's 64x32 tile (2 m-frags).
// 3 MFMA per frag pair: hi*hi + hi*lo + lo*hi.
// ---------------------------------------------------------------------------
__device__ __forceinline__ void gemm16(
    const ushort* __restrict__ gH, const ushort* __restrict__ gL, int kc0,
    ushort* __restrict__ sH, ushort* __restrict__ sL,
    const ushort* __restrict__ XH, const ushort* __restrict__ XL,
    int m_wave, int nn, int ln31, int kg,
    f32x16 (&acc)[2])
{
    const int tid = threadIdx.x;
    const int e = tid * 4;                       // linear copy slot (uint2)
    const ushort* gph = gH + kc0 * 2048 + e;
    const ushort* gpl = gL + kc0 * 2048 + e;
    uint2 pH = *(const uint2*)gph;
    uint2 pL = *(const uint2*)gpl;
    const int nsw = (nn & 7) << 3;
    const int a0 = (m_wave + ln31) * WROW + (kg ^ ((ln31 & 1) << 3));
    #pragma unroll
    for (int c = 0; c < 8; ++c) {
        __syncthreads();
        *(uint2*)&sH[e] = pH;
        *(uint2*)&sL[e] = pL;
        int nx = ((c < 7) ? (c + 1) : 7) * 2048;  // clamp: last prefetch unused
        pH = *(const uint2*)(gph + nx);
        pL = *(const uint2*)(gpl + nx);
        __syncthreads();
        int bcol = c * 16 + kg;
        bf16x8 bh = *(const bf16x8*)&XH[nn * XROW + (bcol ^ nsw)];
        bf16x8 bl = *(const bf16x8*)&XL[nn * XROW + (bcol ^ nsw)];
        #pragma unroll
        for (int mi = 0; mi < 2; ++mi) {
            bf16x8 ah = *(const bf16x8*)&sH[a0 + mi * 32 * WROW];
            bf16x8 al = *(const bf16x8*)&sL[a0 + mi * 32 * WROW];
            acc[mi] = __builtin_amdgcn_mfma_f32_32x32x16_bf16(ah, bh, acc[mi], 0, 0, 0);
            acc[mi] = __builtin_amdgcn_mfma_f32_32x32x16_bf16(ah, bl, acc[mi], 0, 0, 0);
            acc[mi] = __builtin_amdgcn_mfma_f32_32x32x16_bf16(al, bh, acc[mi], 0, 0, 0);
        }
    }
}

// ---------------------------------------------------------------------------
// One WaveNet layer, fused, split-bf16 MFMA.
// Block: 128 ch x TN=128 t; 8 waves as 2(m) x 4(n); wave tile 64x32.
// LDS 75776B -> 2 blocks/CU (16 waves/CU); VGPR capped 128 via bounds(512,4).
// D-frag mapping (verified): col n = lane&31, row m = (r&3)+8*(r>>2)+4*(lane>>5).
// ---------------------------------------------------------------------------
__global__ __launch_bounds__(512, 4) void layer_kernel(
    const float* __restrict__ h_in, float* __restrict__ h_out,
    float* __restrict__ skip,
    const ushort* __restrict__ WdH, const ushort* __restrict__ WdL,
    const ushort* __restrict__ WtH, const ushort* __restrict__ WtL,
    const ushort* __restrict__ WsH, const ushort* __restrict__ WsL,
    const ushort* __restrict__ WkH, const ushort* __restrict__ WkL,
    const float* __restrict__ bd, const float* __restrict__ bt,
    const float* __restrict__ bs, const float* __restrict__ bk,
    int dil, int addskip)
{
    __shared__ ushort XbH[TN * XROW], XbL[TN * XROW];   // 2 x 32 KB
    __shared__ ushort WaH[C_ * WROW], WaL[C_ * WROW];   // 2 x 4 KB
    __shared__ float bias_lds[512];                     // 2 KB  (total 75776B)

    const int tid = threadIdx.x;
    const int b  = blockIdx.x / NTL;
    const int t0 = (blockIdx.x % NTL) * TN;
    const int lane = tid & 63;
    const int wave = tid >> 6;
    const int m_wave = (wave & 1) * 64;
    const int n_wave = (wave >> 1) * 32;
    const int ln31 = lane & 31, kg = (lane >> 5) * 8, hi5 = lane >> 5;
    const int nn = n_wave + ln31;
    const int nsw = (nn & 7) << 3;
    const float* hb = h_in + (size_t)b * C_ * T_;

    {   // biases -> LDS (ordered before first use by the gemm barriers)
        int sec = tid >> 7;
        const float* bp = sec == 0 ? bd : (sec == 1 ? bt : (sec == 2 ? bs : bk));
        bias_lds[tid] = bp[tid & 127];
    }

    // ---- Phase B: xd = Wd @ [h_del ; h_cur] + bd  (K=256, two staged halves)
    f32x16 xdacc[2];
    #pragma unroll
    for (int mi = 0; mi < 2; ++mi)
        #pragma unroll
        for (int r = 0; r < 16; ++r) xdacc[mi][r] = 0.f;

    stageX(hb, t0 - dil, XbH, XbL);
    gemm16(WdH, WdL, 0, WaH, WaL, XbH, XbL, m_wave, nn, ln31, kg, xdacc);
    stageX(hb, t0,       XbH, XbL);
    gemm16(WdH, WdL, 8, WaH, WaL, XbH, XbL, m_wave, nn, ln31, kg, xdacc);

    __syncthreads();                       // all B-GEMM reads of Xb done
    // epilogue: xd = acc + bd -> Xb hi/lo (xdacc dead afterwards; recovered
    // from Xb at phase-C epilogue to keep VGPRs <= 128)
    #pragma unroll
    for (int mi = 0; mi < 2; ++mi) {
        #pragma unroll
        for (int g = 0; g < 4; ++g) {
            int mloc = m_wave + mi * 32 + g * 8 + 4 * hi5;
            ushort4 h4, l4;
            #pragma unroll
            for (int j = 0; j < 4; ++j) {
                float v = xdacc[mi][g * 4 + j] + bias_lds[mloc + j];
                ushort hh, ll; split2(v, hh, ll);
                ((ushort*)&h4)[j] = hh; ((ushort*)&l4)[j] = ll;
            }
            *(ushort4*)&XbH[nn * XROW + (mloc ^ nsw)] = h4;
            *(ushort4*)&XbL[nn * XROW + (mloc ^ nsw)] = l4;
        }
    }

    // ---- Phase C: gates, sequential GEMMs (leading sync in gemm16 orders
    //      the xd writes above before any read/overwrite) ----
    f32x16 at[2], as_[2];
    #pragma unroll
    for (int mi = 0; mi < 2; ++mi)
        #pragma unroll
        for (int r = 0; r < 16; ++r) { at[mi][r] = 0.f; as_[mi][r] = 0.f; }
    gemm16(WtH, WtL, 0, WaH, WaL, XbH, XbL, m_wave, nn, ln31, kg, at);
    gemm16(WsH, WsL, 0, WaH, WaL, XbH, XbL, m_wave, nn, ln31, kg, as_);

    __syncthreads();                       // all C-GEMM reads of Xb done
    float* hob = h_out + (size_t)b * C_ * T_;
    #pragma unroll
    for (int mi = 0; mi < 2; ++mi) {
        #pragma unroll
        for (int g = 0; g < 4; ++g) {
            int mloc = m_wave + mi * 32 + g * 8 + 4 * hi5;
            int xcol = mloc ^ nsw;
            ushort4 xdh = *(ushort4*)&XbH[nn * XROW + xcol];   // own cells only
            ushort4 xdl = *(ushort4*)&XbL[nn * XROW + xcol];
            ushort4 h4, l4;
            #pragma unroll
            for (int j = 0; j < 4; ++j) {
                float a = at[mi][g * 4 + j] + bias_lds[128 + mloc + j];
                float s = as_[mi][g * 4 + j] + bias_lds[256 + mloc + j];
                float f  = 2.f / (1.f + __expf(-2.f * a)) - 1.f;   // tanh
                float gg = 1.f / (1.f + __expf(-s));               // sigmoid
                float xh = f * gg;
                float xd = bf16_to_f(((const ushort*)&xdh)[j])
                         + bf16_to_f(((const ushort*)&xdl)[j]);
                hob[(size_t)(mloc + j) * T_ + t0 + nn] = xh + xd;
                ushort hh, ll; split2(xh, hh, ll);
                ((ushort*)&h4)[j] = hh; ((ushort*)&l4)[j] = ll;
            }
            *(ushort4*)&XbH[nn * XROW + xcol] = h4;    // xh overwrites xd
            *(ushort4*)&XbL[nn * XROW + xcol] = l4;
        }
    }

    // ---- Phase D: skip += Wk @ xh + bk (leading sync orders xh writes) ----
    f32x16 ak[2];
    #pragma unroll
    for (int mi = 0; mi < 2; ++mi)
        #pragma unroll
        for (int r = 0; r < 16; ++r) ak[mi][r] = 0.f;
    gemm16(WkH, WkL, 0, WaH, WaL, XbH, XbL, m_wave, nn, ln31, kg, ak);

    float* skb = skip + (size_t)b * C_ * T_;
    #pragma unroll
    for (int mi = 0; mi < 2; ++mi) {
        #pragma unroll
        for (int g = 0; g < 4; ++g) {
            int mloc = m_wave + mi * 32 + g * 8 + 4 * hi5;
            #pragma unroll
            for (int j = 0; j < 4; ++j) {
                float v = ak[mi][g * 4 + j] + bias_lds[384 + mloc + j];
                size_t adr = (size_t)(mloc + j) * T_ + t0 + nn;
                if (addskip) v += skb[adr];
                skb[adr] = v;
            }
        }
    }
}

// ---------------------------------------------------------------------------
extern "C" void kernel_launch(void* const* d_in, const int* in_sizes, int n_in,
                              void* d_out, int out_size, void* d_ws, size_t ws_size,
                              hipStream_t stream)
{
    const float* x   = (const float*)d_in[0];
    const float* Win = (const float*)d_in[1];
    const float* bin = (const float*)d_in[2];
    const float* Wd  = (const float*)d_in[3];
    const float* bd  = (const float*)d_in[4];
    const float* Wt  = (const float*)d_in[5];
    const float* bt  = (const float*)d_in[6];
    const float* Ws  = (const float*)d_in[7];
    const float* bs  = (const float*)d_in[8];
    const float* Wk  = (const float*)d_in[9];
    const float* bk  = (const float*)d_in[10];
    float* out = (float*)d_out;

    float* ws = (float*)d_ws;
    const size_t HN = (size_t)B_ * C_ * T_;      // 16.8M floats (64MB)
    float* hA = ws;
    float* hB = ws + HN;
    ushort* wb = (ushort*)(ws + 2 * HN);
    const size_t ND = (size_t)L_ * C_ * 256;     // 655360
    const size_t N1 = (size_t)L_ * C_ * C_;      // 327680
    ushort* WdH = wb;            ushort* WdL = WdH + ND;
    ushort* WtH = WdL + ND;      ushort* WtL = WtH + N1;
    ushort* WsH = WtL + N1;      ushort* WsL = WsH + N1;
    ushort* WkH = WsL + N1;      ushort* WkL = WkH + N1;

    const int prep_total = (int)(ND + 3 * N1);   // 1,638,400
    prep_kernel<<<(prep_total + 255) / 256, 256, 0, stream>>>(
        Wd, Wt, Ws, Wk, WdH, WdL, WtH, WtL, WsH, WsL, WkH, WkL);
    in_conv_kernel<<<(B_ * C_ * (T_ / 4)) / 256, 256, 0, stream>>>(x, Win, bin, hA);

    float* hin = hA;
    float* hout = hB;
    for (int l = 0; l < L_; ++l) {
        int dil = 1 << (l % 10);
        layer_kernel<<<B_ * NTL, 512, 0, stream>>>(
            hin, hout, out,
            WdH + (size_t)l * C_ * 256, WdL + (size_t)l * C_ * 256,
            WtH + (size_t)l * C_ * C_,  WtL + (size_t)l * C_ * C_,
            WsH + (size_t)l * C_ * C_,  WsL + (size_t)l * C_ * C_,
            WkH + (size_t)l * C_ * C_,  WkL + (size_t)l * C_ * C_,
            bd + l * C_, bt + l * C_, bs + l * C_, bk + l * C_,
            dil, l > 0 ? 1 : 0);
        float* tmp = hin; hin = hout; hout = tmp;
    }
}